// Round 8
// baseline (63.549 us; speedup 1.0000x reference)
//
#include <hip/hip_runtime.h>

#define NB_IMG   2048
#define GSQ      169                  // 13*13
#define NCELLS   (NB_IMG * GSQ)       // 346112
#define NANCH    5
#define ANCH_FLOATS  (25 * GSQ)       // 4225
#define BATCH_FLOATS (125 * GSQ)      // 21125
#define REC_SLOTS 16
#define PART_BYTES ((size_t)NB_IMG * REC_SLOTS * sizeof(double))  // 262144

// Record slots: [0] coord sq  [1] conf sq obj  [2] conf sq noobj
// [3..7] per-anchor class sq  [8..12] per-anchor obj count

template<bool ATOMIC>
__global__ __launch_bounds__(256) void detloss_main(
    const float* __restrict__ det,
    const float* __restrict__ gt,
    const float* __restrict__ aw,
    const float* __restrict__ ah,
    double* __restrict__ ws)
{
    __shared__ unsigned long long mbits[NANCH][3];   // obj ballot bits, cells 0..168
    __shared__ unsigned short pairs[NANCH * GSQ];    // (k<<8)|cell, anchor-major, cell-asc
    __shared__ float red[4][13];

    const int b    = blockIdx.x;
    const int tid  = threadIdx.x;
    const int wave = tid >> 6;
    const int lane = tid & 63;
    const size_t bbase = (size_t)b * BATCH_FLOATS;

    float Scoord = 0.f, S4 = 0.f, S5 = 0.f;
    float Ccnt[NANCH] = {0.f, 0.f, 0.f, 0.f, 0.f};

    // ---------- Phase A: unmasked conf/IoU only (18 coalesced dword loads) ----------
    if (tid < GSQ) {
        const float* dbase = det + bbase + tid;
        const float* gbase = gt  + bbase + tid;

        const float px = dbase[0 * GSQ];
        const float py = dbase[1 * GSQ];
        const float dw = dbase[2 * GSQ];
        const float dh = dbase[3 * GSQ];
        const float gx = gbase[0 * GSQ];
        const float gy = gbase[1 * GSQ];
        const float gw = gbase[2 * GSQ];
        const float gh = gbase[3 * GSQ];
        const float a2 = (gw - gx + 1.0f) * (gh - gy + 1.0f);

        #pragma unroll
        for (int k = 0; k < NANCH; ++k) {
            const float* dk = dbase + k * ANCH_FLOATS;
            const float* gk = gbase + k * ANCH_FLOATS;

            const float g4v = gk[4 * GSQ];
            const float d4v = dk[4 * GSQ];
            const bool  obj = (g4v == 1.0f);

            const float pw = dw * aw[k];
            const float ph = dh * ah[k];
            const float x1 = fmaxf(px, gx);
            const float y1 = fmaxf(py, gy);
            const float x2 = fminf(pw, gw);
            const float y2 = fminf(ph, gh);
            const float inter = (x2 - x1 + 1.0f) * (y2 - y1 + 1.0f);
            const float a1    = (pw - px + 1.0f) * (ph - py + 1.0f);
            const float iou   = inter / (a1 + a2 - inter);

            const float conf = d4v * (iou >= 0.0f ? iou : 0.0f);  // NaN -> 0 like jnp.where
            const float d4   = conf - g4v;
            const float d4sq = d4 * d4;

            S4 += obj ? d4sq : 0.0f;    // selects: avoid inf*0 -> NaN
            S5 += obj ? 0.0f : d4sq;
            Ccnt[k] = obj ? 1.0f : 0.0f;

            const unsigned long long bb = __ballot(obj);   // cell = wave*64 + lane
            if (lane == 0) mbits[k][wave] = bb;            // wave in {0,1,2}
        }
    }
    __syncthreads();   // ballots visible

    // ---------- total + prefix (all threads, from LDS broadcast reads) ----------
    int total = 0;
    int basek[NANCH];
    #pragma unroll
    for (int k = 0; k < NANCH; ++k) {
        basek[k] = total;
        total += __popcll(mbits[k][0]) + __popcll(mbits[k][1]) + __popcll(mbits[k][2]);
    }

    // ---------- deterministic list build (anchor-major, cell ascending) ----------
    if (tid < GSQ) {
        #pragma unroll
        for (int k = 0; k < NANCH; ++k) {
            const unsigned long long mw = mbits[k][wave];
            if ((mw >> lane) & 1ull) {
                int pos = basek[k];
                if (wave > 0) pos += __popcll(mbits[k][0]);
                if (wave > 1) pos += __popcll(mbits[k][1]);
                pos += __popcll(mw & ((1ull << lane) - 1ull));
                pairs[pos] = (unsigned short)((k << 8) | tid);
            }
        }
    }
    __syncthreads();   // list visible

    // ---------- Phase B: flat dense loop over obj items ----------
    // item w -> pair j = w/24, sub c = w%24; c<20: class ch 5+c; c>=20: coord ch c-20
    float c0 = 0.f, c1 = 0.f, c2 = 0.f, c3 = 0.f, c4 = 0.f;
    const int nitems = total * 24;
    #pragma unroll 4
    for (int w = tid; w < nitems; w += 256) {
        const unsigned j = (unsigned)w / 24u;
        const unsigned c = (unsigned)w - 24u * j;
        const int e    = pairs[j];
        const int a    = e >> 8;
        const int cell = e & 0xff;
        const int ch   = (c < 20u) ? (int)(c + 5u) : (int)(c - 20u);
        const size_t addr = bbase + (size_t)(a * ANCH_FLOATS + ch * GSQ + cell);
        const float dd = det[addr] - gt[addr];
        const float v  = dd * dd;
        const float vc = (c < 20u) ? v : 0.f;   // class part
        Scoord += (c < 20u) ? 0.f : v;          // coord part (all anchors)
        c0 += (a == 0) ? vc : 0.f;
        c1 += (a == 1) ? vc : 0.f;
        c2 += (a == 2) ? vc : 0.f;
        c3 += (a == 3) ? vc : 0.f;
        c4 += (a == 4) ? vc : 0.f;
    }

    // ---------- block reduction of 13 partials ----------
    float vals[13] = {Scoord, S4, S5,
                      c0, c1, c2, c3, c4,
                      Ccnt[0], Ccnt[1], Ccnt[2], Ccnt[3], Ccnt[4]};
    #pragma unroll
    for (int i = 0; i < 13; ++i) {
        #pragma unroll
        for (int off2 = 32; off2 > 0; off2 >>= 1)
            vals[i] += __shfl_down(vals[i], off2, 64);
    }

    if (lane == 0) {
        #pragma unroll
        for (int i = 0; i < 13; ++i) red[wave][i] = vals[i];
    }
    __syncthreads();

    if (tid < 13) {
        const double s = (double)red[0][tid] + (double)red[1][tid] +
                         (double)red[2][tid] + (double)red[3][tid];
        if (ATOMIC) atomicAdd(&ws[tid], s);
        else        ws[(size_t)b * REC_SLOTS + tid] = s;
    }
}

__device__ __forceinline__ void write_outputs(const double* a, float* out)
{
    const double cnt = a[8] + a[9] + a[10] + a[11] + a[12];
    const double coord = (cnt > 0.0) ? a[0] / cnt : 0.0;
    const double s4    = (cnt > 0.0) ? a[1] / cnt : 0.0;
    const double obj_loss = 5.0 * coord + s4;

    const double cntno  = (double)NCELLS * (double)NANCH - cnt;
    const double no_obj = (cntno > 0.0) ? 0.5 * a[2] / cntno : 0.0;

    double confsum = 0.0;
    for (int k = 0; k < NANCH; ++k) {
        const double ck = a[8 + k];
        if (ck > 0.0) confsum += a[3 + k] / ck;
    }
    const double loss = obj_loss + no_obj + confsum;
    out[0] = (float)loss;
    out[1] = (float)obj_loss;
    out[2] = (float)no_obj;
    out[3] = (float)confsum;
}

__global__ __launch_bounds__(256) void detloss_reduce(
    const double* __restrict__ ws, float* __restrict__ out)
{
    double loc[13];
    #pragma unroll
    for (int i = 0; i < 13; ++i) loc[i] = 0.0;

    for (int rec = threadIdx.x; rec < NB_IMG; rec += 256) {
        const double* p = ws + (size_t)rec * REC_SLOTS;
        #pragma unroll
        for (int i = 0; i < 13; ++i) loc[i] += p[i];
    }

    #pragma unroll
    for (int i = 0; i < 13; ++i) {
        #pragma unroll
        for (int off = 32; off > 0; off >>= 1)
            loc[i] += __shfl_down(loc[i], off, 64);
    }

    __shared__ double red[4][13];
    const int wave = threadIdx.x >> 6;
    const int lane = threadIdx.x & 63;
    if (lane == 0) {
        #pragma unroll
        for (int i = 0; i < 13; ++i) red[wave][i] = loc[i];
    }
    __syncthreads();

    if (threadIdx.x == 0) {
        double a[13];
        #pragma unroll
        for (int i = 0; i < 13; ++i)
            a[i] = red[0][i] + red[1][i] + red[2][i] + red[3][i];
        write_outputs(a, out);
    }
}

__global__ void detloss_final(const double* __restrict__ acc, float* __restrict__ out)
{
    if (threadIdx.x == 0 && blockIdx.x == 0) {
        double a[13];
        for (int i = 0; i < 13; ++i) a[i] = acc[i];
        write_outputs(a, out);
    }
}

extern "C" void kernel_launch(void* const* d_in, const int* in_sizes, int n_in,
                              void* d_out, int out_size, void* d_ws, size_t ws_size,
                              hipStream_t stream)
{
    const float* det = (const float*)d_in[0];
    const float* gt  = (const float*)d_in[1];
    const float* aw  = (const float*)d_in[2];
    const float* ah  = (const float*)d_in[3];
    double* ws  = (double*)d_ws;
    float*  out = (float*)d_out;

    if (ws_size >= PART_BYTES) {
        detloss_main<false><<<NB_IMG, 256, 0, stream>>>(det, gt, aw, ah, ws);
        detloss_reduce<<<1, 256, 0, stream>>>(ws, out);
    } else {
        hipMemsetAsync(ws, 0, 13 * sizeof(double), stream);
        detloss_main<true><<<NB_IMG, 256, 0, stream>>>(det, gt, aw, ah, ws);
        detloss_final<<<1, 64, 0, stream>>>(ws, out);
    }
}